// Round 2
// baseline (324.629 us; speedup 1.0000x reference)
//
#include <hip/hip_runtime.h>

// BinaryDense: out = sign(x) @ sign(w). x[8192,4096] f32, w[4096,4096] f32, out f32.
// fp4 e2m1 nibble encoding {-1,0,+1} = {0xA,0x0,0x2}; MX-scaled fp4 MFMA (scales=1.0).
// Round 5: T3+T4+T5 pipeline — staging quantum = K-half (128 elems, 32 KB A+B),
// 4-slot LDS ring (128 KB), 3 halves in flight, counted s_waitcnt vmcnt(8) (never 0
// in main loop), raw s_barrier once per half, s_setprio(1) around MFMA clusters.
// 256x256 tile, 8 waves 2Mx4N, wave tile 128x64, global_load_lds staging with
// pre-swizzled global source (linear LDS dest) + matching XOR read swizzle.

#define M_DIM 8192
#define K_DIM 4096
#define N_DIM 4096
#define KB2   (K_DIM / 2)      // packed bytes per row = 2048
#define HALFB 64               // bytes per row per K-half (128 k-elems)
#define NH    (KB2 / HALFB)    // 32 K-halves
#define HTILE (256 * HALFB)    // one operand half-tile = 16 KB
#define SLOTB (2 * HTILE)      // ring slot (A+B) = 32 KB; 4 slots = 128 KB

typedef int   v4i  __attribute__((ext_vector_type(4)));
typedef int   v8i  __attribute__((ext_vector_type(8)));
typedef float v16f __attribute__((ext_vector_type(16)));

__device__ __forceinline__ unsigned int nib4(float x) {
    // fp4 e2m1: +1.0 -> 0b0010, -1.0 -> 0b1010, 0 -> 0b0000
    return x > 0.0f ? 0x2u : (x < 0.0f ? 0xAu : 0x0u);
}

// ---- fused pack: blocks [0, 32768) pack x; blocks [32768, 34816) pack wT ----
__global__ __launch_bounds__(256) void pack_both(const float* __restrict__ x,
                                                 unsigned short* __restrict__ xq,
                                                 const float* __restrict__ w,
                                                 unsigned char* __restrict__ wT) {
    if (blockIdx.x < 32768u) {
        // pack x: 4 floats -> 4 nibbles (one ushort) per thread
        size_t t = (size_t)blockIdx.x * 256 + threadIdx.x;
        float4 f = ((const float4*)x)[t];
        unsigned int v = nib4(f.x) | (nib4(f.y) << 4) | (nib4(f.z) << 8) | (nib4(f.w) << 12);
        xq[t] = (unsigned short)v;
        return;
    }
    // pack wT: w[k][n] f32 -> wT[n][k/2] nibbles, 64k x 128n tile via LDS
    __shared__ unsigned char sT[64][132];
    const unsigned id = blockIdx.x - 32768u;
    const int t  = threadIdx.x;
    const int n0 = (int)(id & 31) * 128;
    const int kb = (int)(id >> 5);
    const int k0 = kb * 64;

    const int cq = t & 31;   // float4 column
    const int r0 = t >> 5;   // 0..7
#pragma unroll
    for (int p = 0; p < 8; ++p) {
        int r = r0 + 8 * p;
        float4 f = *(const float4*)(w + (size_t)(k0 + r) * N_DIM + n0 + cq * 4);
        uchar4 c;
        c.x = (unsigned char)nib4(f.x);
        c.y = (unsigned char)nib4(f.y);
        c.z = (unsigned char)nib4(f.z);
        c.w = (unsigned char)nib4(f.w);
        *(uchar4*)(&sT[r][cq * 4]) = c;
    }
    __syncthreads();

    const int n  = t >> 1;   // 0..127
    const int kq = t & 1;    // 32-k chunk
    union { unsigned char b[16]; int4 v; } u;
#pragma unroll
    for (int j = 0; j < 16; ++j) {
        unsigned lo = sT[kq * 32 + 2 * j][n];
        unsigned hi = sT[kq * 32 + 2 * j + 1][n];
        u.b[j] = (unsigned char)(lo | (hi << 4));
    }
    *(int4*)(wT + (size_t)(n0 + n) * KB2 + (size_t)kb * 32 + kq * 16) = u.v;
}

__device__ __forceinline__ v8i widen(v4i x) {
    v8i r;
    r[0] = x[0]; r[1] = x[1]; r[2] = x[2]; r[3] = x[3];
    r[4] = 0; r[5] = 0; r[6] = 0; r[7] = 0;
    return r;
}

// async global -> LDS, 16 bytes per lane (dest must be wave-uniform base + lane*16)
__device__ __forceinline__ void gload16(const unsigned char* g, unsigned char* l) {
    __builtin_amdgcn_global_load_lds(
        (__attribute__((address_space(1))) void*)(void*)g,
        (__attribute__((address_space(3))) void*)l, 16, 0, 0);
}

// ---- fp4 MFMA GEMM: C[M,N] = A * B^T, A/B packed nibbles K-major ----
// LDS half-tile layout: row r (0..255), k-granule kc (0..3, 16 B each) lives at
// byte (r>>1)*128 + slot*16, slot = ((r&1)*4 | kc) ^ ((r>>1)&7).
// Frag reads (32 rows fixed kc) hit each bank exactly 4x = ds_read_b128 floor.
// Staging granule g (linear LDS dest g*16): q=g>>3, t=(g&7)^(q&7),
// src row = 2q+(t>>2), kc = t&3 — the inverse permutation, pre-applied to the
// global source address so global_load_lds' linear dest yields this layout.
__global__ __launch_bounds__(512, 2) void bgemm_fp4(const unsigned char* __restrict__ A,
                                                    const unsigned char* __restrict__ B,
                                                    float* __restrict__ C) {
    __shared__ __align__(16) unsigned char lds[4 * SLOTB];   // 128 KB ring

    const int tid  = threadIdx.x;
    const int lane = tid & 63;
    const int wave = tid >> 6;   // 0..7
    const int wm   = wave >> 2;  // 0..1 (M)
    const int wn   = wave & 3;   // 0..3 (N)
    const int l31  = lane & 31;
    const int lhi  = lane >> 5;

    const int m0 = blockIdx.y * 256;
    const int n0 = blockIdx.x * 256;

    v16f acc[4][2] = {};

    // Staging: per thread 2 granules of A and 2 of B per half: g = i*512 + tid.
    const unsigned char* gAsrc[2];
    const unsigned char* gBsrc[2];
    int dstOff[2];
#pragma unroll
    for (int i = 0; i < 2; ++i) {
        int g   = i * 512 + tid;       // 0..1023
        int q   = g >> 3;              // rowpair 0..127
        int t   = (g & 7) ^ (q & 7);
        int row = 2 * q + (t >> 2);
        int kc  = t & 3;
        gAsrc[i] = A + (size_t)(m0 + row) * KB2 + kc * 16;
        gBsrc[i] = B + (size_t)(n0 + row) * KB2 + kc * 16;
        dstOff[i] = g * 16;
    }

    // Fragment read offsets: mfma k-step ks (0..1), lane granule kc = 2*ks + lhi.
    int offA[2][4], offB[2][2];
#pragma unroll
    for (int ks = 0; ks < 2; ++ks) {
        const int kc = 2 * ks + lhi;
#pragma unroll
        for (int tm = 0; tm < 4; ++tm) {
            int r    = wm * 128 + tm * 32 + l31;
            int q    = r >> 1;
            int slot = (((r & 1) << 2) | kc) ^ (q & 7);
            offA[ks][tm] = q * 128 + slot * 16;
        }
#pragma unroll
        for (int tn = 0; tn < 2; ++tn) {
            int r    = wn * 64 + tn * 32 + l31;
            int q    = r >> 1;
            int slot = (((r & 1) << 2) | kc) ^ (q & 7);
            offB[ks][tn] = q * 128 + slot * 16;
        }
    }

    auto stage = [&](int h) {
        unsigned char* s = lds + (h & 3) * SLOTB;
        const size_t ko = (size_t)h * HALFB;
#pragma unroll
        for (int i = 0; i < 2; ++i) {
            gload16(gAsrc[i] + ko, s + dstOff[i]);            // 2 vmcnt ops
            gload16(gBsrc[i] + ko, s + HTILE + dstOff[i]);    // 2 vmcnt ops
        }
    };

    auto compute = [&](int h) {
        const unsigned char* sA = lds + (h & 3) * SLOTB;
        const unsigned char* sB = sA + HTILE;
#pragma unroll
        for (int ks = 0; ks < 2; ++ks) {
            v4i a4[4], b4[2];
#pragma unroll
            for (int tm = 0; tm < 4; ++tm) a4[tm] = *(const v4i*)(sA + offA[ks][tm]);
#pragma unroll
            for (int tn = 0; tn < 2; ++tn) b4[tn] = *(const v4i*)(sB + offB[ks][tn]);
            __builtin_amdgcn_s_setprio(1);
#pragma unroll
            for (int tm = 0; tm < 4; ++tm)
#pragma unroll
                for (int tn = 0; tn < 2; ++tn)
                    acc[tm][tn] = __builtin_amdgcn_mfma_scale_f32_32x32x64_f8f6f4(
                        widen(a4[tm]), widen(b4[tn]), acc[tm][tn],
                        4, 4,                  // cbsz=FP4, blgp=FP4
                        0, 0x7F7F7F7F,         // opsel_a, scale_a (e8m0 1.0)
                        0, 0x7F7F7F7F);        // opsel_b, scale_b
            __builtin_amdgcn_s_setprio(0);
        }
    };

    // Pipeline: 3 halves in flight (4 vmcnt ops each). At top of half h the wave
    // has issued stages up to h+2; vmcnt(8) guarantees half h landed while h+1/h+2
    // stay in flight. Barrier AFTER the wait -> all waves' DMA for half h visible,
    // and all waves' reads of half h-1 retired before stage(h+3) rewrites its slot.
    stage(0); stage(1); stage(2);
    for (int h = 0; h < NH - 3; ++h) {                        // h = 0..28
        asm volatile("s_waitcnt vmcnt(8)" ::: "memory");
        __builtin_amdgcn_s_barrier();
        stage(h + 3);
        compute(h);
    }
    asm volatile("s_waitcnt vmcnt(8)" ::: "memory");          // halves 30,31 in flight
    __builtin_amdgcn_s_barrier();
    compute(NH - 3);
    asm volatile("s_waitcnt vmcnt(4)" ::: "memory");          // half 31 in flight
    __builtin_amdgcn_s_barrier();
    compute(NH - 2);
    asm volatile("s_waitcnt vmcnt(0)" ::: "memory");
    __builtin_amdgcn_s_barrier();
    compute(NH - 1);

    // Epilogue: C/D 32x32 layout: col = lane&31, row = (r&3) + 8*(r>>2) + 4*lhi.
    // Nontemporal: C is streamed once; keep packed operands resident in L2/L3.
#pragma unroll
    for (int tm = 0; tm < 4; ++tm) {
#pragma unroll
        for (int tn = 0; tn < 2; ++tn) {
            const int col  = n0 + wn * 64 + tn * 32 + l31;
            const int rowb = m0 + wm * 128 + tm * 32 + 4 * lhi;
#pragma unroll
            for (int r = 0; r < 16; ++r) {
                int row = rowb + (r & 3) + 8 * (r >> 2);
                __builtin_nontemporal_store(acc[tm][tn][r], &C[(size_t)row * N_DIM + col]);
            }
        }
    }
}

extern "C" void kernel_launch(void* const* d_in, const int* in_sizes, int n_in,
                              void* d_out, int out_size, void* d_ws, size_t ws_size,
                              hipStream_t stream) {
    const float* x = (const float*)d_in[0];   // [8192, 4096]
    const float* w = (const float*)d_in[1];   // [4096, 4096]
    float* out = (float*)d_out;               // [8192, 4096]

    unsigned char* xq = (unsigned char*)d_ws;                 // 16 MB packed x
    unsigned char* wq = xq + (size_t)M_DIM * KB2;             // 8 MB packed wT

    // 32768 blocks pack x + 2048 blocks pack wT, one dispatch
    pack_both<<<dim3(32768 + 2048), dim3(256), 0, stream>>>(
        x, (unsigned short*)xq, w, wq);
    bgemm_fp4<<<dim3(N_DIM / 256, M_DIM / 256), dim3(512), 0, stream>>>(xq, wq, out);
}

// Round 3
// 323.161 us; speedup vs baseline: 1.0045x; 1.0045x over previous
//
#include <hip/hip_runtime.h>

// BinaryDense: out = sign(x) @ sign(w). x[8192,4096] f32, w[4096,4096] f32, out f32.
// fp4 e2m1 nibble encoding {-1,0,+1} = {0xA,0x0,0x2}; MX-scaled fp4 MFMA (scales=1.0).
// Round 6: cross-barrier software pipeline. 4-slot LDS ring (128 KB), publish-TWO-
// ahead (vmcnt(4) w/ 2 stages in flight at each barrier), and fragment ds_reads
// issued one sub-phase ahead ACROSS the barrier (double frag register sets), so the
// post-barrier LDS read burst overlaps the MFMA clusters instead of serializing.
// 256x256 tile, 8 waves 2Mx4N, wave tile 128x64, global_load_lds staging with
// pre-swizzled global source (linear LDS dest) + matching XOR read swizzle.
// Bijective XCD chunk swizzle (512 blocks = 8 XCDs x 64).

#define M_DIM 8192
#define K_DIM 4096
#define N_DIM 4096
#define KB2   (K_DIM / 2)      // packed bytes per row = 2048
#define HALFB 64               // bytes per row per K-half (128 k-elems)
#define NH    (KB2 / HALFB)    // 32 K-halves
#define HTILE (256 * HALFB)    // one operand half-tile = 16 KB
#define SLOTB (2 * HTILE)      // ring slot (A+B) = 32 KB; 4 slots = 128 KB

typedef int   v4i  __attribute__((ext_vector_type(4)));
typedef int   v8i  __attribute__((ext_vector_type(8)));
typedef float v16f __attribute__((ext_vector_type(16)));

__device__ __forceinline__ unsigned int nib4(float x) {
    // fp4 e2m1: +1.0 -> 0b0010, -1.0 -> 0b1010, 0 -> 0b0000
    return x > 0.0f ? 0x2u : (x < 0.0f ? 0xAu : 0x0u);
}

// ---- fused pack: blocks [0, 32768) pack x; blocks [32768, 34816) pack wT ----
__global__ __launch_bounds__(256) void pack_both(const float* __restrict__ x,
                                                 unsigned short* __restrict__ xq,
                                                 const float* __restrict__ w,
                                                 unsigned char* __restrict__ wT) {
    if (blockIdx.x < 32768u) {
        // pack x: 4 floats -> 4 nibbles (one ushort) per thread
        size_t t = (size_t)blockIdx.x * 256 + threadIdx.x;
        float4 f = ((const float4*)x)[t];
        unsigned int v = nib4(f.x) | (nib4(f.y) << 4) | (nib4(f.z) << 8) | (nib4(f.w) << 12);
        xq[t] = (unsigned short)v;
        return;
    }
    // pack wT: w[k][n] f32 -> wT[n][k/2] nibbles, 64k x 128n tile via LDS
    __shared__ unsigned char sT[64][132];
    const unsigned id = blockIdx.x - 32768u;
    const int t  = threadIdx.x;
    const int n0 = (int)(id & 31) * 128;
    const int kb = (int)(id >> 5);
    const int k0 = kb * 64;

    const int cq = t & 31;   // float4 column
    const int r0 = t >> 5;   // 0..7
#pragma unroll
    for (int p = 0; p < 8; ++p) {
        int r = r0 + 8 * p;
        float4 f = *(const float4*)(w + (size_t)(k0 + r) * N_DIM + n0 + cq * 4);
        uchar4 c;
        c.x = (unsigned char)nib4(f.x);
        c.y = (unsigned char)nib4(f.y);
        c.z = (unsigned char)nib4(f.z);
        c.w = (unsigned char)nib4(f.w);
        *(uchar4*)(&sT[r][cq * 4]) = c;
    }
    __syncthreads();

    const int n  = t >> 1;   // 0..127
    const int kq = t & 1;    // 32-k chunk
    union { unsigned char b[16]; int4 v; } u;
#pragma unroll
    for (int j = 0; j < 16; ++j) {
        unsigned lo = sT[kq * 32 + 2 * j][n];
        unsigned hi = sT[kq * 32 + 2 * j + 1][n];
        u.b[j] = (unsigned char)(lo | (hi << 4));
    }
    *(int4*)(wT + (size_t)(n0 + n) * KB2 + (size_t)kb * 32 + kq * 16) = u.v;
}

__device__ __forceinline__ v8i widen(v4i x) {
    v8i r;
    r[0] = x[0]; r[1] = x[1]; r[2] = x[2]; r[3] = x[3];
    r[4] = 0; r[5] = 0; r[6] = 0; r[7] = 0;
    return r;
}

// async global -> LDS, 16 bytes per lane (dest must be wave-uniform base + lane*16)
__device__ __forceinline__ void gload16(const unsigned char* g, unsigned char* l) {
    __builtin_amdgcn_global_load_lds(
        (__attribute__((address_space(1))) void*)(void*)g,
        (__attribute__((address_space(3))) void*)l, 16, 0, 0);
}

// Frag loads into a named register set (literal KS keeps all indexing static).
#define RD_FRAGS(A4, B2, BASE, KS)                                   \
    do {                                                             \
        const unsigned char* sA_ = lds + (BASE);                     \
        const unsigned char* sB_ = sA_ + HTILE;                      \
        A4[0] = *(const v4i*)(sA_ + offA[KS][0]);                    \
        A4[1] = *(const v4i*)(sA_ + offA[KS][1]);                    \
        A4[2] = *(const v4i*)(sA_ + offA[KS][2]);                    \
        A4[3] = *(const v4i*)(sA_ + offA[KS][3]);                    \
        B2[0] = *(const v4i*)(sB_ + offB[KS][0]);                    \
        B2[1] = *(const v4i*)(sB_ + offB[KS][1]);                    \
    } while (0)

#define MFMA8(A4, B2)                                                \
    do {                                                             \
        __builtin_amdgcn_s_setprio(1);                               \
        _Pragma("unroll")                                            \
        for (int tm_ = 0; tm_ < 4; ++tm_)                            \
            _Pragma("unroll")                                        \
            for (int tn_ = 0; tn_ < 2; ++tn_)                        \
                acc[tm_][tn_] = __builtin_amdgcn_mfma_scale_f32_32x32x64_f8f6f4( \
                    widen(A4[tm_]), widen(B2[tn_]), acc[tm_][tn_],   \
                    4, 4, 0, 0x7F7F7F7F, 0, 0x7F7F7F7F);             \
        __builtin_amdgcn_s_setprio(0);                               \
    } while (0)

// ---- fp4 MFMA GEMM: C[M,N] = A * B^T, A/B packed nibbles K-major ----
// LDS half-tile layout: row r (0..255), k-granule kc (0..3, 16 B each) lives at
// byte (r>>1)*128 + slot*16, slot = ((r&1)*4 | kc) ^ ((r>>1)&7).
// Staging granule g (linear LDS dest g*16): q=g>>3, t=(g&7)^(q&7),
// src row = 2q+(t>>2), kc = t&3 — inverse permutation pre-applied to the global
// source address so global_load_lds' linear dest yields this layout.
__global__ __launch_bounds__(512, 2) void bgemm_fp4(const unsigned char* __restrict__ A,
                                                    const unsigned char* __restrict__ B,
                                                    float* __restrict__ C) {
    __shared__ __align__(16) unsigned char lds[4 * SLOTB];   // 128 KB ring

    const int tid  = threadIdx.x;
    const int lane = tid & 63;
    const int wave = tid >> 6;   // 0..7
    const int wm   = wave >> 2;  // 0..1 (M)
    const int wn   = wave & 3;   // 0..3 (N)
    const int l31  = lane & 31;
    const int lhi  = lane >> 5;

    // Bijective XCD chunk swizzle: 512 blocks = 8 XCDs x 64; each XCD gets 4
    // consecutive M-rows of the grid -> A panels L2-resident per XCD.
    const int id = (int)blockIdx.x;
    const int sw = (id & 7) * 64 + (id >> 3);
    const int bx = sw & 15;      // N tile (16)
    const int by = sw >> 4;      // M tile (32)
    const int m0 = by * 256;
    const int n0 = bx * 256;

    v16f acc[4][2] = {};

    // Staging: per thread 2 granules of A and 2 of B per half: g = i*512 + tid.
    const unsigned char* gAsrc[2];
    const unsigned char* gBsrc[2];
    int dstOff[2];
#pragma unroll
    for (int i = 0; i < 2; ++i) {
        int g   = i * 512 + tid;       // 0..1023
        int q   = g >> 3;              // rowpair 0..127
        int t   = (g & 7) ^ (q & 7);
        int row = 2 * q + (t >> 2);
        int kc  = t & 3;
        gAsrc[i] = A + (size_t)(m0 + row) * KB2 + kc * 16;
        gBsrc[i] = B + (size_t)(n0 + row) * KB2 + kc * 16;
        dstOff[i] = g * 16;
    }

    // Fragment read offsets: mfma k-step ks (0..1), lane granule kc = 2*ks + lhi.
    int offA[2][4], offB[2][2];
#pragma unroll
    for (int ks = 0; ks < 2; ++ks) {
        const int kc = 2 * ks + lhi;
#pragma unroll
        for (int tm = 0; tm < 4; ++tm) {
            int r    = wm * 128 + tm * 32 + l31;
            int q    = r >> 1;
            int slot = (((r & 1) << 2) | kc) ^ (q & 7);
            offA[ks][tm] = q * 128 + slot * 16;
        }
#pragma unroll
        for (int tn = 0; tn < 2; ++tn) {
            int r    = wn * 64 + tn * 32 + l31;
            int q    = r >> 1;
            int slot = (((r & 1) << 2) | kc) ^ (q & 7);
            offB[ks][tn] = q * 128 + slot * 16;
        }
    }

    auto stage = [&](int h) {
        unsigned char* s = lds + (h & 3) * SLOTB;
        const size_t ko = (size_t)h * HALFB;
#pragma unroll
        for (int i = 0; i < 2; ++i) {
            gload16(gAsrc[i] + ko, s + dstOff[i]);            // 2 vmcnt ops
            gload16(gBsrc[i] + ko, s + HTILE + dstOff[i]);    // 2 vmcnt ops
        }
    };

    v4i a0[4], b0[2];   // frags for ks=0 of some half
    v4i a1[4], b1[2];   // frags for ks=1 of some half

    // Prologue: 3 halves staged (12 vmem ops); vmcnt(4) -> halves 0,1 landed;
    // barrier publishes them. Then preload frags (0, ks=0).
    stage(0); stage(1); stage(2);
    asm volatile("s_waitcnt vmcnt(4)" ::: "memory");
    __builtin_amdgcn_s_barrier();
    RD_FRAGS(a0, b0, 0, 0);

    // Main loop invariant at top of half h: halves <= h+1 are published; frags
    // (h, ks=0) already issued (possibly still in lgkm flight — compiler emits
    // the counted lgkmcnt right before the first MFMA that uses them).
    // Body: read(h,1) | mfma(h,0) | read(h+1,0) | stage(h+3) | mfma(h,1)
    //       | vmcnt(4) (halves <= h+2 landed, stage h+3 stays in flight) | barrier.
    // Slot safety: stage(h+3) rewrites slot (h-1), whose last reads retired a full
    // half + one barrier earlier.
    for (int h = 0; h < NH - 3; ++h) {                        // h = 0..28
        const int sh  = (h & 3) * SLOTB;
        const int sh1 = ((h + 1) & 3) * SLOTB;
        RD_FRAGS(a1, b1, sh, 1);
        MFMA8(a0, b0);
        RD_FRAGS(a0, b0, sh1, 0);
        stage(h + 3);
        MFMA8(a1, b1);
        asm volatile("s_waitcnt vmcnt(4)" ::: "memory");
        __builtin_amdgcn_s_barrier();
    }
    // h = NH-3: no more stages; drain all DMA and publish half NH-1.
    {
        const int sh  = ((NH - 3) & 3) * SLOTB;
        const int sh1 = ((NH - 2) & 3) * SLOTB;
        RD_FRAGS(a1, b1, sh, 1);
        MFMA8(a0, b0);
        RD_FRAGS(a0, b0, sh1, 0);
        MFMA8(a1, b1);
        asm volatile("s_waitcnt vmcnt(0)" ::: "memory");
        __builtin_amdgcn_s_barrier();
    }
    // h = NH-2: everything resident; no barrier needed (no further LDS writes).
    {
        const int sh  = ((NH - 2) & 3) * SLOTB;
        const int sh1 = ((NH - 1) & 3) * SLOTB;
        RD_FRAGS(a1, b1, sh, 1);
        MFMA8(a0, b0);
        RD_FRAGS(a0, b0, sh1, 0);
        MFMA8(a1, b1);
    }
    // h = NH-1
    {
        const int sh = ((NH - 1) & 3) * SLOTB;
        RD_FRAGS(a1, b1, sh, 1);
        MFMA8(a0, b0);
        MFMA8(a1, b1);
    }

    // Epilogue: C/D 32x32 layout: col = lane&31, row = (r&3) + 8*(r>>2) + 4*lhi.
    // Nontemporal: C is streamed once; keep packed operands resident in L2/L3.
#pragma unroll
    for (int tm = 0; tm < 4; ++tm) {
#pragma unroll
        for (int tn = 0; tn < 2; ++tn) {
            const int col  = n0 + wn * 64 + tn * 32 + l31;
            const int rowb = m0 + wm * 128 + tm * 32 + 4 * lhi;
#pragma unroll
            for (int r = 0; r < 16; ++r) {
                int row = rowb + (r & 3) + 8 * (r >> 2);
                __builtin_nontemporal_store(acc[tm][tn][r], &C[(size_t)row * N_DIM + col]);
            }
        }
    }
}

extern "C" void kernel_launch(void* const* d_in, const int* in_sizes, int n_in,
                              void* d_out, int out_size, void* d_ws, size_t ws_size,
                              hipStream_t stream) {
    const float* x = (const float*)d_in[0];   // [8192, 4096]
    const float* w = (const float*)d_in[1];   // [4096, 4096]
    float* out = (float*)d_out;               // [8192, 4096]

    unsigned char* xq = (unsigned char*)d_ws;                 // 16 MB packed x
    unsigned char* wq = xq + (size_t)M_DIM * KB2;             // 8 MB packed wT

    // 32768 blocks pack x + 2048 blocks pack wT, one dispatch
    pack_both<<<dim3(32768 + 2048), dim3(256), 0, stream>>>(
        x, (unsigned short*)xq, w, wq);
    bgemm_fp4<<<dim3((M_DIM / 256) * (N_DIM / 256)), dim3(512), 0, stream>>>(xq, wq, out);
}